// Round 10
// baseline (160.414 us; speedup 1.0000x reference)
//
#include <hip/hip_runtime.h>
#include <stdint.h>

typedef short v8s __attribute__((ext_vector_type(8)));
typedef float v4f __attribute__((ext_vector_type(4)));

#define MFMA(a, b, c) __builtin_amdgcn_mfma_f32_16x16x32_bf16((a), (b), (c), 0, 0, 0)

__device__ __forceinline__ short f2bf(float f) {
  union { float f; uint32_t u; } v; v.f = f;
  uint32_t r = v.u + 0x7fffu + ((v.u >> 16) & 1u);
  return (short)(r >> 16);
}

// pack two fp32 -> two bf16 (truncate) in one v_perm_b32
__device__ __forceinline__ uint32_t pack2(float a, float b) {
  union { float f; uint32_t u; } ua, ub; ua.f = a; ub.f = b;
  return __builtin_amdgcn_perm(ub.u, ua.u, 0x07060302u);
}

__device__ __forceinline__ void gload16(const void* g, void* l) {
  __builtin_amdgcn_global_load_lds((const __attribute__((address_space(1))) void*)g,
                                   (__attribute__((address_space(3))) void*)l,
                                   16, 0, 0);
}

// ------- merged prep (blocks 256..4351) + groupnorm (blocks 0..255) -------
__global__ __launch_bounds__(256) void prep_gn_kernel(
    const float* __restrict__ qkvw, const float* __restrict__ qkvb,
    const float* __restrict__ projw,
    short* __restrict__ Wq, short* __restrict__ Wp, float* __restrict__ bias2,
    const float* __restrict__ x, const float* __restrict__ gw,
    const float* __restrict__ gb, short* __restrict__ hT) {
  __shared__ float red[8];
  __shared__ short tile[16 * 1032];
  int tid = threadIdx.x;
  if (blockIdx.x >= 256) {
    int idx = (blockIdx.x - 256) * 256 + tid;
    if (idx < 1536 * 512) {
      int r = idx >> 9, c = idx & 511;
      int sec = r >> 9;            // 0=q, 1=k, 2=v
      int rr = r & 511;
      int nh = rr >> 6, cc = rr & 63;
      int o = nh * 192 + sec * 64 + cc;
      Wq[idx] = f2bf(qkvw[o * 512 + c]);
      if (c == 0) bias2[r] = qkvb[o];
    } else {
      int j = idx - 1536 * 512;
      if (j < 512 * 512) Wp[j] = f2bf(projw[j]);
    }
    return;
  }
  int b = blockIdx.x >> 5, g = blockIdx.x & 31;
  const float* xg = x + (b * 512 + g * 16) * 1024;
  float s = 0.f, ss = 0.f;
#pragma unroll
  for (int r = 0; r < 16; ++r) {
    float4 v = *(const float4*)(xg + r * 1024 + tid * 4);
    s += v.x + v.y + v.z + v.w;
    ss += v.x * v.x + v.y * v.y + v.z * v.z + v.w * v.w;
  }
#pragma unroll
  for (int off = 32; off > 0; off >>= 1) {
    s += __shfl_xor(s, off, 64);
    ss += __shfl_xor(ss, off, 64);
  }
  if ((tid & 63) == 0) { red[tid >> 6] = s; red[4 + (tid >> 6)] = ss; }
  __syncthreads();
  float S = red[0] + red[1] + red[2] + red[3];
  float SS = red[4] + red[5] + red[6] + red[7];
  float mean = S * (1.f / 16384.f);
  float var = SS * (1.f / 16384.f) - mean * mean;
  float inv = rsqrtf(var + 1e-5f);
#pragma unroll
  for (int r = 0; r < 16; ++r) {
    int c = g * 16 + r;
    float a = inv * gw[c];
    float bb = gb[c] - mean * a;
    float4 v = *(const float4*)(xg + r * 1024 + tid * 4);
    short* tr = tile + r * 1032 + tid * 4;
    tr[0] = f2bf(fmaf(v.x, a, bb));
    tr[1] = f2bf(fmaf(v.y, a, bb));
    tr[2] = f2bf(fmaf(v.z, a, bb));
    tr[3] = f2bf(fmaf(v.w, a, bb));
  }
  __syncthreads();
  int r = tid & 15, tq = tid >> 4;
  int c = g * 16 + r;
  short* dst = hT + b * 1024 * 512 + c;
  const short* src = tile + r * 1032;
#pragma unroll
  for (int i = 0; i < 64; ++i) {
    int t = i * 16 + tq;
    dst[t * 512] = src[t];
  }
}

// -------- shared GEMM core v2: K=512, 128x128 tile, BK=64, XOR-swizzled ------
__device__ __forceinline__ void gemm_k512_b64(
    const short* __restrict__ Ag, const short* __restrict__ Bg,
    short* lA, short* lB, int wid, int lane, v4f acc[4][4]) {
  int wr = (wid >> 1) * 64, wc = (wid & 1) * 64;
  int c16 = lane & 15, q = lane >> 4;
  int srow = lane >> 3;                       // 0..7 within an 8-row slab
  int sw = ((lane & 7) ^ srow) * 8;           // swizzled 16B-chunk (shorts)
  const short* gaw = Ag + (wid * 32 + srow) * 512 + sw;
  const short* gbw = Bg + (wid * 32 + srow) * 512 + sw;
  short* lAw = lA + wid * 2048;               // rows 32*wid.., 64 shorts/row
  short* lBw = lB + wid * 2048;
  int pc0 = (q ^ (c16 & 7)) * 8;              // kstep 0 chunk
  int pc1 = ((4 + q) ^ (c16 & 7)) * 8;        // kstep 1 chunk
  for (int kt = 0; kt < 8; ++kt) {
    int k0 = kt * 64;
#pragma unroll
    for (int t = 0; t < 4; ++t)
      gload16(gaw + t * 8 * 512 + k0, lAw + t * 512);
#pragma unroll
    for (int t = 0; t < 4; ++t)
      gload16(gbw + t * 8 * 512 + k0, lBw + t * 512);
    __syncthreads();
#pragma unroll
    for (int ks = 0; ks < 2; ++ks) {
      int pc = ks ? pc1 : pc0;
      v8s af[4], bf[4];
#pragma unroll
      for (int i = 0; i < 4; ++i)
        af[i] = *(const v8s*)(lA + (wr + i * 16 + c16) * 64 + pc);
#pragma unroll
      for (int j = 0; j < 4; ++j)
        bf[j] = *(const v8s*)(lB + (wc + j * 16 + c16) * 64 + pc);
#pragma unroll
      for (int i = 0; i < 4; ++i)
#pragma unroll
        for (int j = 0; j < 4; ++j)
          acc[i][j] = MFMA(af[i], bf[j], acc[i][j]);
    }
    __syncthreads();
  }
}

// ---------------- QKV GEMM: M=n(8192), N=o(1536) ----------------
// Q pre-scaled by 0.125*log2(e). Q/K/V epilogues ALL route through the LDS
// transpose tile so every global store is a coalesced v8s (full 128B lines).
__global__ __launch_bounds__(256) void qkv_gemm_kernel(
    const short* __restrict__ hT, const short* __restrict__ Wq,
    const float* __restrict__ bias2,
    short* __restrict__ Qb, short* __restrict__ Kb, short* __restrict__ Vb) {
  __shared__ __align__(16) short smem[17408];  // staging 2x8192 / vt 17408 union
  short* lA = smem;
  short* lB = smem + 8192;
  short* vt = smem;
  int bm = blockIdx.x & 63, bo = blockIdx.x >> 6;
  int tid = threadIdx.x, wid = tid >> 6, lane = tid & 63;
  int wr = (wid >> 1) * 64, wc = (wid & 1) * 64;
  int q = lane >> 4, c16 = lane & 15;
  v4f acc[4][4];
#pragma unroll
  for (int i = 0; i < 4; ++i)
#pragma unroll
    for (int j = 0; j < 4; ++j) acc[i][j] = (v4f){0.f, 0.f, 0.f, 0.f};
  gemm_k512_b64(hT + bm * 128 * 512, Wq + bo * 128 * 512, lA, lB, wid, lane, acc);
  float bv[4];
#pragma unroll
  for (int j = 0; j < 4; ++j) bv[j] = bias2[bo * 128 + wc + j * 16 + c16];
  if (bo < 8) {
    // Q/K: acc -> LDS transpose vt[t_local*136 + ocol_local], then coalesced
    // v8s stores (16 full 128B segments per wave-store vs 64x32B scattered).
    short* dst = (bo < 4) ? Qb : Kb;
    float sc = (bo < 4) ? 0.18033688f : 1.f;  // 0.125 * log2(e) folded into Q
#pragma unroll
    for (int j = 0; j < 4; ++j) {
      int ol = wc + j * 16 + c16;
#pragma unroll
      for (int i = 0; i < 4; ++i)
#pragma unroll
        for (int rr = 0; rr < 4; ++rr) {
          int nl = wr + i * 16 + q * 4 + rr;
          vt[nl * 136 + ol] = f2bf((acc[i][j][rr] + bv[j]) * sc);
        }
    }
    __syncthreads();
    int chunk = tid & 15, row0 = tid >> 4;
    int obase = (bo & 3) * 128 + chunk * 8;
    int nh = obase >> 6, cc = obase & 63;
#pragma unroll
    for (int ps = 0; ps < 8; ++ps) {
      int row = row0 + ps * 16;
      int n = bm * 128 + row;
      int b_ = n >> 10, t = n & 1023;
      *(v8s*)(dst + b_ * 524288 + nh * 65536 + t * 64 + cc) =
          *(const v8s*)(vt + row * 136 + chunk * 8);
    }
  } else {
#pragma unroll
    for (int j = 0; j < 4; ++j) {
      int ol = wc + j * 16 + c16;
#pragma unroll
      for (int i = 0; i < 4; ++i)
#pragma unroll
        for (int rr = 0; rr < 4; ++rr) {
          int nl = wr + i * 16 + q * 4 + rr;
          vt[ol * 136 + nl] = f2bf(acc[i][j][rr] + bv[j]);
        }
    }
    __syncthreads();
    int ol = tid >> 1, hf = tid & 1;
    int ovg = (bo - 8) * 128 + ol;
    const short* src = vt + ol * 136 + hf * 64;
    short* dstv = Vb + ovg * 8192 + bm * 128 + hf * 64;
#pragma unroll
    for (int m = 0; m < 8; ++m)
      *(v8s*)(dstv + m * 8) = *(const v8s*)(src + m * 8);
  }
}

// ---------------- fused attention v8: LDS-staged K/V (unchanged from R8) ----
__global__ __launch_bounds__(512, 4) void attn_kernel(
    const short* __restrict__ Qb, const short* __restrict__ Kb,
    const short* __restrict__ Vb, short* __restrict__ aT) {
  __shared__ __align__(16) short lds[35840];  // K 16K + V 16K + P 38.9K
  int hb = blockIdx.x >> 3, tt = blockIdx.x & 7;
  int b = hb >> 3, nh = hb & 7;
  int tid = threadIdx.x, wid = tid >> 6, lane = tid & 63;
  int chunk = wid >> 2, w4 = wid & 3;
  int q = lane >> 4, c16 = lane & 15;
  const short* Qh = Qb + hb * 65536;
  const short* Kh = Kb + hb * 65536;
  const short* Vh = Vb + nh * 64 * 8192 + b * 1024;
  int t0 = tt * 128 + w4 * 32;
  int sbase = chunk * 512;
  short* Kst = lds + chunk * 4096;
  short* Vst = lds + 8192 + chunk * 4096;
  short* pw = lds + 16384 + wid * 2432;  // wave-private P, stride 76
  v8s qf[2][2];
#pragma unroll
  for (int i = 0; i < 2; ++i)
#pragma unroll
    for (int kk = 0; kk < 2; ++kk)
      qf[i][kk] = *(const v8s*)(Qh + (t0 + i * 16 + c16) * 64 + kk * 32 + q * 8);
  v4f of[2][4];
  float lsum[2] = {0.f, 0.f};
#pragma unroll
  for (int i = 0; i < 2; ++i)
#pragma unroll
    for (int j = 0; j < 4; ++j) of[i][j] = (v4f){0.f, 0.f, 0.f, 0.f};
  int sidx0 = w4 * 128 + lane;
  int sidx1 = w4 * 128 + 64 + lane;
  int r0 = sidx0 >> 3, m0 = (sidx0 & 7) ^ (r0 & 7);
  int r1 = sidx1 >> 3, m1 = (sidx1 & 7) ^ (r1 & 7);
#pragma unroll 1
  for (int st = 0; st < 8; ++st) {
    int s0 = sbase + st * 64;
    gload16(Kh + (s0 + r0) * 64 + m0 * 8, Kst + (w4 * 128) * 8);
    gload16(Kh + (s0 + r1) * 64 + m1 * 8, Kst + (w4 * 128 + 64) * 8);
    gload16(Vh + r0 * 8192 + s0 + m0 * 8, Vst + (w4 * 128) * 8);
    gload16(Vh + r1 * 8192 + s0 + m1 * 8, Vst + (w4 * 128 + 64) * 8);
    __syncthreads();
    v8s kf[4][2];
#pragma unroll
    for (int j = 0; j < 4; ++j) {
      int row = j * 16 + c16;
#pragma unroll
      for (int kk = 0; kk < 2; ++kk) {
        int pc = (kk * 4 + q) ^ (c16 & 7);
        kf[j][kk] = *(const v8s*)(Kst + row * 64 + pc * 8);
      }
    }
#pragma unroll
    for (int j = 0; j < 4; ++j) {
      v4f s0v = (v4f){0.f, 0.f, 0.f, 0.f};
      s0v = MFMA(kf[j][0], qf[0][0], s0v);
      s0v = MFMA(kf[j][1], qf[0][1], s0v);
      v4f s1v = (v4f){0.f, 0.f, 0.f, 0.f};
      s1v = MFMA(kf[j][0], qf[1][0], s1v);
      s1v = MFMA(kf[j][1], qf[1][1], s1v);
      float p00 = __builtin_amdgcn_exp2f(s0v[0]);
      float p01 = __builtin_amdgcn_exp2f(s0v[1]);
      float p02 = __builtin_amdgcn_exp2f(s0v[2]);
      float p03 = __builtin_amdgcn_exp2f(s0v[3]);
      lsum[0] += (p00 + p01) + (p02 + p03);
      uint2 pk0;
      pk0.x = pack2(p00, p01);
      pk0.y = pack2(p02, p03);
      *(uint2*)(pw + c16 * 76 + j * 16 + q * 4) = pk0;
      float p10 = __builtin_amdgcn_exp2f(s1v[0]);
      float p11 = __builtin_amdgcn_exp2f(s1v[1]);
      float p12 = __builtin_amdgcn_exp2f(s1v[2]);
      float p13 = __builtin_amdgcn_exp2f(s1v[3]);
      lsum[1] += (p10 + p11) + (p12 + p13);
      uint2 pk1;
      pk1.x = pack2(p10, p11);
      pk1.y = pack2(p12, p13);
      *(uint2*)(pw + (16 + c16) * 76 + j * 16 + q * 4) = pk1;
    }
    v8s vf[4][2];
#pragma unroll
    for (int j = 0; j < 4; ++j) {
      int row = j * 16 + c16;
#pragma unroll
      for (int kk = 0; kk < 2; ++kk) {
        int pc = (kk * 4 + q) ^ (c16 & 7);
        vf[j][kk] = *(const v8s*)(Vst + row * 64 + pc * 8);
      }
    }
    asm volatile("s_waitcnt lgkmcnt(0)" ::: "memory");
    v8s pa[2][2];
#pragma unroll
    for (int i = 0; i < 2; ++i)
#pragma unroll
      for (int kk = 0; kk < 2; ++kk)
        pa[i][kk] = *(const v8s*)(pw + (i * 16 + c16) * 76 + kk * 32 + q * 8);
#pragma unroll
    for (int i = 0; i < 2; ++i)
#pragma unroll
      for (int j = 0; j < 4; ++j) {
        of[i][j] = MFMA(pa[i][0], vf[j][0], of[i][j]);
        of[i][j] = MFMA(pa[i][1], vf[j][1], of[i][j]);
      }
    __syncthreads();
  }
#pragma unroll
  for (int i = 0; i < 2; ++i) {
    lsum[i] += __shfl_xor(lsum[i], 16, 64);
    lsum[i] += __shfl_xor(lsum[i], 32, 64);
  }
  float* ex = (float*)(lds + 16384) + w4 * 2144;
  __syncthreads();
  if (chunk == 1) {
#pragma unroll
    for (int i = 0; i < 2; ++i) {
#pragma unroll
      for (int j = 0; j < 4; ++j)
#pragma unroll
        for (int rr = 0; rr < 4; ++rr)
          ex[(i * 16 + q * 4 + rr) * 66 + j * 16 + c16] = of[i][j][rr];
      if (q == 0) ex[2112 + i * 16 + c16] = lsum[i];
    }
  }
  __syncthreads();
  if (chunk == 0) {
    short* base = aT + b * 1024 * 512 + nh * 64;
#pragma unroll
    for (int i = 0; i < 2; ++i)
#pragma unroll
      for (int rr = 0; rr < 4; ++rr) {
        int row = i * 16 + q * 4 + rr;
        float inv = 1.f / (__shfl(lsum[i], q * 4 + rr, 64) + ex[2112 + row]);
        int t = t0 + row;
#pragma unroll
        for (int j = 0; j < 4; ++j) {
          float v = (of[i][j][rr] + ex[row * 66 + j * 16 + c16]) * inv;
          base[t * 512 + j * 16 + c16] = f2bf(v);
        }
      }
  }
}

// ---------------- proj GEMM: M=o(512), N=n(8192), fused bias+residual ----------------
__global__ __launch_bounds__(256) void proj_gemm_kernel(
    const short* __restrict__ Wp, const short* __restrict__ aT,
    const float* __restrict__ pbias, const float* __restrict__ x,
    float* __restrict__ out) {
  __shared__ __align__(16) short smem[16384];  // 2 x 128x64 staging (32 KB)
  short* lA = smem;
  short* lB = smem + 8192;
  int bm = blockIdx.x & 3, bn = blockIdx.x >> 2;
  int tid = threadIdx.x, wid = tid >> 6, lane = tid & 63;
  int wr = (wid >> 1) * 64, wc = (wid & 1) * 64;
  int q = lane >> 4, c16 = lane & 15;
  v4f acc[4][4];
#pragma unroll
  for (int i = 0; i < 4; ++i)
#pragma unroll
    for (int j = 0; j < 4; ++j) acc[i][j] = (v4f){0.f, 0.f, 0.f, 0.f};
  gemm_k512_b64(Wp + bm * 128 * 512, aT + bn * 128 * 512, lA, lB, wid, lane, acc);
  int colOff[4];
#pragma unroll
  for (int j = 0; j < 4; ++j) {
    int n = bn * 128 + wc + j * 16 + c16;
    colOff[j] = (n >> 10) * 524288 + (n & 1023);
  }
#pragma unroll
  for (int i = 0; i < 4; ++i)
#pragma unroll
    for (int rr = 0; rr < 4; ++rr) {
      int o = bm * 128 + wr + i * 16 + q * 4 + rr;
      float bs = pbias[o];
      int ro = o * 1024;
#pragma unroll
      for (int j = 0; j < 4; ++j) {
        int a = colOff[j] + ro;
        out[a] = acc[i][j][rr] + bs + x[a];
      }
    }
}

extern "C" void kernel_launch(void* const* d_in, const int* in_sizes, int n_in,
                              void* d_out, int out_size, void* d_ws, size_t ws_size,
                              hipStream_t stream) {
  const float* x = (const float*)d_in[0];
  const float* nw = (const float*)d_in[1];
  const float* nb = (const float*)d_in[2];
  const float* qkvw = (const float*)d_in[3];
  const float* qkvb = (const float*)d_in[4];
  const float* projw = (const float*)d_in[5];
  const float* projb = (const float*)d_in[6];
  float* out = (float*)d_out;
  char* w = (char*)d_ws;
  short* hT = (short*)(w);
  short* aT = (short*)(w + 8388608);
  short* Qb = (short*)(w + 16777216);
  short* Kb = (short*)(w + 25165824);
  short* Vb = (short*)(w + 33554432);
  short* Wq2 = (short*)(w + 41943040);
  short* Wp2 = (short*)(w + 43515904);
  float* b2 = (float*)(w + 44040192);

  hipLaunchKernelGGL(prep_gn_kernel, dim3(4352), dim3(256), 0, stream,
                     qkvw, qkvb, projw, Wq2, Wp2, b2, x, nw, nb, hT);
  hipLaunchKernelGGL(qkv_gemm_kernel, dim3(768), dim3(256), 0, stream,
                     hT, Wq2, b2, Qb, Kb, Vb);
  hipLaunchKernelGGL(attn_kernel, dim3(512), dim3(512), 0, stream, Qb, Kb, Vb, aT);
  hipLaunchKernelGGL(proj_gemm_kernel, dim3(256), dim3(256), 0, stream,
                     Wp2, aT, projb, x, out);
}

// Round 11
// 157.264 us; speedup vs baseline: 1.0200x; 1.0200x over previous
//
#include <hip/hip_runtime.h>
#include <stdint.h>

typedef short v8s __attribute__((ext_vector_type(8)));
typedef short v4s __attribute__((ext_vector_type(4)));
typedef float v4f __attribute__((ext_vector_type(4)));

#define MFMA(a, b, c) __builtin_amdgcn_mfma_f32_16x16x32_bf16((a), (b), (c), 0, 0, 0)

__device__ __forceinline__ short f2bf(float f) {
  union { float f; uint32_t u; } v; v.f = f;
  uint32_t r = v.u + 0x7fffu + ((v.u >> 16) & 1u);
  return (short)(r >> 16);
}

// pack two fp32 -> two bf16 (truncate) in one v_perm_b32
__device__ __forceinline__ uint32_t pack2(float a, float b) {
  union { float f; uint32_t u; } ua, ub; ua.f = a; ub.f = b;
  return __builtin_amdgcn_perm(ub.u, ua.u, 0x07060302u);
}

__device__ __forceinline__ void gload16(const void* g, void* l) {
  __builtin_amdgcn_global_load_lds((const __attribute__((address_space(1))) void*)g,
                                   (__attribute__((address_space(3))) void*)l,
                                   16, 0, 0);
}

// ------- merged prep (blocks 256..4351) + groupnorm (blocks 0..255) -------
// gn v2: single x read (held in 16xfloat4 regs), v4s transpose-stores.
__global__ __launch_bounds__(256) void prep_gn_kernel(
    const float* __restrict__ qkvw, const float* __restrict__ qkvb,
    const float* __restrict__ projw,
    short* __restrict__ Wq, short* __restrict__ Wp, float* __restrict__ bias2,
    const float* __restrict__ x, const float* __restrict__ gw,
    const float* __restrict__ gb, short* __restrict__ hT) {
  __shared__ float red[8];
  __shared__ short tile[16 * 1032];
  int tid = threadIdx.x;
  if (blockIdx.x >= 256) {
    int idx = (blockIdx.x - 256) * 256 + tid;
    if (idx < 1536 * 512) {
      int r = idx >> 9, c = idx & 511;
      int sec = r >> 9;            // 0=q, 1=k, 2=v
      int rr = r & 511;
      int nh = rr >> 6, cc = rr & 63;
      int o = nh * 192 + sec * 64 + cc;
      Wq[idx] = f2bf(qkvw[o * 512 + c]);
      if (c == 0) bias2[r] = qkvb[o];
    } else {
      int j = idx - 1536 * 512;
      if (j < 512 * 512) Wp[j] = f2bf(projw[j]);
    }
    return;
  }
  int b = blockIdx.x >> 5, g = blockIdx.x & 31;
  const float* xg = x + (b * 512 + g * 16) * 1024;
  float4 v[16];
  float s = 0.f, ss = 0.f;
#pragma unroll
  for (int r = 0; r < 16; ++r) {
    v[r] = *(const float4*)(xg + r * 1024 + tid * 4);
    s += v[r].x + v[r].y + v[r].z + v[r].w;
    ss += v[r].x * v[r].x + v[r].y * v[r].y + v[r].z * v[r].z + v[r].w * v[r].w;
  }
#pragma unroll
  for (int off = 32; off > 0; off >>= 1) {
    s += __shfl_xor(s, off, 64);
    ss += __shfl_xor(ss, off, 64);
  }
  if ((tid & 63) == 0) { red[tid >> 6] = s; red[4 + (tid >> 6)] = ss; }
  __syncthreads();
  float S = red[0] + red[1] + red[2] + red[3];
  float SS = red[4] + red[5] + red[6] + red[7];
  float mean = S * (1.f / 16384.f);
  float var = SS * (1.f / 16384.f) - mean * mean;
  float inv = rsqrtf(var + 1e-5f);
#pragma unroll
  for (int r = 0; r < 16; ++r) {
    int c = g * 16 + r;
    float a = inv * gw[c];
    float bb = gb[c] - mean * a;
    short* tr = tile + r * 1032 + tid * 4;
    tr[0] = f2bf(fmaf(v[r].x, a, bb));
    tr[1] = f2bf(fmaf(v[r].y, a, bb));
    tr[2] = f2bf(fmaf(v[r].z, a, bb));
    tr[3] = f2bf(fmaf(v[r].w, a, bb));
  }
  __syncthreads();
  // store: thread = (cq = tid&3 -> 4 channels, tq = tid>>2 -> t slot)
  int cq = tid & 3, tq = tid >> 2;
  int c4 = cq * 4;
  short* dst = hT + b * 1024 * 512 + g * 16 + c4;
#pragma unroll
  for (int i = 0; i < 16; ++i) {
    int t = i * 64 + tq;
    v4s val = {tile[(c4 + 0) * 1032 + t], tile[(c4 + 1) * 1032 + t],
               tile[(c4 + 2) * 1032 + t], tile[(c4 + 3) * 1032 + t]};
    *(v4s*)(dst + t * 512) = val;
  }
}

// -------- shared GEMM core v2: K=512, 128x128 tile, BK=64, XOR-swizzled ------
__device__ __forceinline__ void gemm_k512_b64(
    const short* __restrict__ Ag, const short* __restrict__ Bg,
    short* lA, short* lB, int wid, int lane, v4f acc[4][4]) {
  int wr = (wid >> 1) * 64, wc = (wid & 1) * 64;
  int c16 = lane & 15, q = lane >> 4;
  int srow = lane >> 3;                       // 0..7 within an 8-row slab
  int sw = ((lane & 7) ^ srow) * 8;           // swizzled 16B-chunk (shorts)
  const short* gaw = Ag + (wid * 32 + srow) * 512 + sw;
  const short* gbw = Bg + (wid * 32 + srow) * 512 + sw;
  short* lAw = lA + wid * 2048;               // rows 32*wid.., 64 shorts/row
  short* lBw = lB + wid * 2048;
  int pc0 = (q ^ (c16 & 7)) * 8;              // kstep 0 chunk
  int pc1 = ((4 + q) ^ (c16 & 7)) * 8;        // kstep 1 chunk
  for (int kt = 0; kt < 8; ++kt) {
    int k0 = kt * 64;
#pragma unroll
    for (int t = 0; t < 4; ++t)
      gload16(gaw + t * 8 * 512 + k0, lAw + t * 512);
#pragma unroll
    for (int t = 0; t < 4; ++t)
      gload16(gbw + t * 8 * 512 + k0, lBw + t * 512);
    __syncthreads();
#pragma unroll
    for (int ks = 0; ks < 2; ++ks) {
      int pc = ks ? pc1 : pc0;
      v8s af[4], bf[4];
#pragma unroll
      for (int i = 0; i < 4; ++i)
        af[i] = *(const v8s*)(lA + (wr + i * 16 + c16) * 64 + pc);
#pragma unroll
      for (int j = 0; j < 4; ++j)
        bf[j] = *(const v8s*)(lB + (wc + j * 16 + c16) * 64 + pc);
#pragma unroll
      for (int i = 0; i < 4; ++i)
#pragma unroll
        for (int j = 0; j < 4; ++j)
          acc[i][j] = MFMA(af[i], bf[j], acc[i][j]);
    }
    __syncthreads();
  }
}

// ---------------- QKV GEMM: M=n(8192), N=o(1536) ----------------
__global__ __launch_bounds__(256) void qkv_gemm_kernel(
    const short* __restrict__ hT, const short* __restrict__ Wq,
    const float* __restrict__ bias2,
    short* __restrict__ Qb, short* __restrict__ Kb, short* __restrict__ Vb) {
  __shared__ __align__(16) short smem[17408];  // staging 2x8192 / vt 17408 union
  short* lA = smem;
  short* lB = smem + 8192;
  short* vt = smem;
  int bm = blockIdx.x & 63, bo = blockIdx.x >> 6;
  int tid = threadIdx.x, wid = tid >> 6, lane = tid & 63;
  int wr = (wid >> 1) * 64, wc = (wid & 1) * 64;
  int q = lane >> 4, c16 = lane & 15;
  v4f acc[4][4];
#pragma unroll
  for (int i = 0; i < 4; ++i)
#pragma unroll
    for (int j = 0; j < 4; ++j) acc[i][j] = (v4f){0.f, 0.f, 0.f, 0.f};
  gemm_k512_b64(hT + bm * 128 * 512, Wq + bo * 128 * 512, lA, lB, wid, lane, acc);
  float bv[4];
#pragma unroll
  for (int j = 0; j < 4; ++j) bv[j] = bias2[bo * 128 + wc + j * 16 + c16];
  if (bo < 8) {
    short* dst = (bo < 4) ? Qb : Kb;
    float sc = (bo < 4) ? 0.18033688f : 1.f;  // 0.125 * log2(e) folded into Q
#pragma unroll
    for (int j = 0; j < 4; ++j) {
      int ol = wc + j * 16 + c16;
#pragma unroll
      for (int i = 0; i < 4; ++i)
#pragma unroll
        for (int rr = 0; rr < 4; ++rr) {
          int nl = wr + i * 16 + q * 4 + rr;
          vt[nl * 136 + ol] = f2bf((acc[i][j][rr] + bv[j]) * sc);
        }
    }
    __syncthreads();
    int chunk = tid & 15, row0 = tid >> 4;
    int obase = (bo & 3) * 128 + chunk * 8;
    int nh = obase >> 6, cc = obase & 63;
#pragma unroll
    for (int ps = 0; ps < 8; ++ps) {
      int row = row0 + ps * 16;
      int n = bm * 128 + row;
      int b_ = n >> 10, t = n & 1023;
      *(v8s*)(dst + b_ * 524288 + nh * 65536 + t * 64 + cc) =
          *(const v8s*)(vt + row * 136 + chunk * 8);
    }
  } else {
#pragma unroll
    for (int j = 0; j < 4; ++j) {
      int ol = wc + j * 16 + c16;
#pragma unroll
      for (int i = 0; i < 4; ++i)
#pragma unroll
        for (int rr = 0; rr < 4; ++rr) {
          int nl = wr + i * 16 + q * 4 + rr;
          vt[ol * 136 + nl] = f2bf(acc[i][j][rr] + bv[j]);
        }
    }
    __syncthreads();
    int ol = tid >> 1, hf = tid & 1;
    int ovg = (bo - 8) * 128 + ol;
    const short* src = vt + ol * 136 + hf * 64;
    short* dstv = Vb + ovg * 8192 + bm * 128 + hf * 64;
#pragma unroll
    for (int m = 0; m < 8; ++m)
      *(v8s*)(dstv + m * 8) = *(const v8s*)(src + m * 8);
  }
}

// ---------------- fused attention v9: v8 + XCD-swizzled block index ----------
// The 8 q-tile blocks of one head get indices == same value mod 8, so under
// round-robin workgroup->XCD dispatch they share an XCD and the head's 256KB
// K/V lives in that XCD's 4MB L2 (8x reuse) instead of bouncing through L3.
__global__ __launch_bounds__(512, 4) void attn_kernel(
    const short* __restrict__ Qb, const short* __restrict__ Kb,
    const short* __restrict__ Vb, short* __restrict__ aT) {
  __shared__ __align__(16) short lds[35840];  // K 16K + V 16K + P 38.9K
  int idx = blockIdx.x;
  int hb = (idx & 7) * 8 + (idx >> 6);
  int tt = (idx >> 3) & 7;
  int b = hb >> 3, nh = hb & 7;
  int tid = threadIdx.x, wid = tid >> 6, lane = tid & 63;
  int chunk = wid >> 2, w4 = wid & 3;
  int q = lane >> 4, c16 = lane & 15;
  const short* Qh = Qb + hb * 65536;
  const short* Kh = Kb + hb * 65536;
  const short* Vh = Vb + nh * 64 * 8192 + b * 1024;
  int t0 = tt * 128 + w4 * 32;
  int sbase = chunk * 512;
  short* Kst = lds + chunk * 4096;
  short* Vst = lds + 8192 + chunk * 4096;
  short* pw = lds + 16384 + wid * 2432;  // wave-private P, stride 76
  v8s qf[2][2];
#pragma unroll
  for (int i = 0; i < 2; ++i)
#pragma unroll
    for (int kk = 0; kk < 2; ++kk)
      qf[i][kk] = *(const v8s*)(Qh + (t0 + i * 16 + c16) * 64 + kk * 32 + q * 8);
  v4f of[2][4];
  float lsum[2] = {0.f, 0.f};
#pragma unroll
  for (int i = 0; i < 2; ++i)
#pragma unroll
    for (int j = 0; j < 4; ++j) of[i][j] = (v4f){0.f, 0.f, 0.f, 0.f};
  int sidx0 = w4 * 128 + lane;
  int sidx1 = w4 * 128 + 64 + lane;
  int r0 = sidx0 >> 3, m0 = (sidx0 & 7) ^ (r0 & 7);
  int r1 = sidx1 >> 3, m1 = (sidx1 & 7) ^ (r1 & 7);
#pragma unroll 1
  for (int st = 0; st < 8; ++st) {
    int s0 = sbase + st * 64;
    gload16(Kh + (s0 + r0) * 64 + m0 * 8, Kst + (w4 * 128) * 8);
    gload16(Kh + (s0 + r1) * 64 + m1 * 8, Kst + (w4 * 128 + 64) * 8);
    gload16(Vh + r0 * 8192 + s0 + m0 * 8, Vst + (w4 * 128) * 8);
    gload16(Vh + r1 * 8192 + s0 + m1 * 8, Vst + (w4 * 128 + 64) * 8);
    __syncthreads();
    v8s kf[4][2];
#pragma unroll
    for (int j = 0; j < 4; ++j) {
      int row = j * 16 + c16;
#pragma unroll
      for (int kk = 0; kk < 2; ++kk) {
        int pc = (kk * 4 + q) ^ (c16 & 7);
        kf[j][kk] = *(const v8s*)(Kst + row * 64 + pc * 8);
      }
    }
#pragma unroll
    for (int j = 0; j < 4; ++j) {
      v4f s0v = (v4f){0.f, 0.f, 0.f, 0.f};
      s0v = MFMA(kf[j][0], qf[0][0], s0v);
      s0v = MFMA(kf[j][1], qf[0][1], s0v);
      v4f s1v = (v4f){0.f, 0.f, 0.f, 0.f};
      s1v = MFMA(kf[j][0], qf[1][0], s1v);
      s1v = MFMA(kf[j][1], qf[1][1], s1v);
      float p00 = __builtin_amdgcn_exp2f(s0v[0]);
      float p01 = __builtin_amdgcn_exp2f(s0v[1]);
      float p02 = __builtin_amdgcn_exp2f(s0v[2]);
      float p03 = __builtin_amdgcn_exp2f(s0v[3]);
      lsum[0] += (p00 + p01) + (p02 + p03);
      uint2 pk0;
      pk0.x = pack2(p00, p01);
      pk0.y = pack2(p02, p03);
      *(uint2*)(pw + c16 * 76 + j * 16 + q * 4) = pk0;
      float p10 = __builtin_amdgcn_exp2f(s1v[0]);
      float p11 = __builtin_amdgcn_exp2f(s1v[1]);
      float p12 = __builtin_amdgcn_exp2f(s1v[2]);
      float p13 = __builtin_amdgcn_exp2f(s1v[3]);
      lsum[1] += (p10 + p11) + (p12 + p13);
      uint2 pk1;
      pk1.x = pack2(p10, p11);
      pk1.y = pack2(p12, p13);
      *(uint2*)(pw + (16 + c16) * 76 + j * 16 + q * 4) = pk1;
    }
    v8s vf[4][2];
#pragma unroll
    for (int j = 0; j < 4; ++j) {
      int row = j * 16 + c16;
#pragma unroll
      for (int kk = 0; kk < 2; ++kk) {
        int pc = (kk * 4 + q) ^ (c16 & 7);
        vf[j][kk] = *(const v8s*)(Vst + row * 64 + pc * 8);
      }
    }
    asm volatile("s_waitcnt lgkmcnt(0)" ::: "memory");
    v8s pa[2][2];
#pragma unroll
    for (int i = 0; i < 2; ++i)
#pragma unroll
      for (int kk = 0; kk < 2; ++kk)
        pa[i][kk] = *(const v8s*)(pw + (i * 16 + c16) * 76 + kk * 32 + q * 8);
#pragma unroll
    for (int i = 0; i < 2; ++i)
#pragma unroll
      for (int j = 0; j < 4; ++j) {
        of[i][j] = MFMA(pa[i][0], vf[j][0], of[i][j]);
        of[i][j] = MFMA(pa[i][1], vf[j][1], of[i][j]);
      }
    __syncthreads();
  }
#pragma unroll
  for (int i = 0; i < 2; ++i) {
    lsum[i] += __shfl_xor(lsum[i], 16, 64);
    lsum[i] += __shfl_xor(lsum[i], 32, 64);
  }
  float* ex = (float*)(lds + 16384) + w4 * 2144;
  __syncthreads();
  if (chunk == 1) {
#pragma unroll
    for (int i = 0; i < 2; ++i) {
#pragma unroll
      for (int j = 0; j < 4; ++j)
#pragma unroll
        for (int rr = 0; rr < 4; ++rr)
          ex[(i * 16 + q * 4 + rr) * 66 + j * 16 + c16] = of[i][j][rr];
      if (q == 0) ex[2112 + i * 16 + c16] = lsum[i];
    }
  }
  __syncthreads();
  if (chunk == 0) {
    short* base = aT + b * 1024 * 512 + nh * 64;
#pragma unroll
    for (int i = 0; i < 2; ++i)
#pragma unroll
      for (int rr = 0; rr < 4; ++rr) {
        int row = i * 16 + q * 4 + rr;
        float inv = 1.f / (__shfl(lsum[i], q * 4 + rr, 64) + ex[2112 + row]);
        int t = t0 + row;
#pragma unroll
        for (int j = 0; j < 4; ++j) {
          float v = (of[i][j][rr] + ex[row * 66 + j * 16 + c16]) * inv;
          base[t * 512 + j * 16 + c16] = f2bf(v);
        }
      }
  }
}

// ---------------- proj GEMM: M=o(512), N=n(8192), fused bias+residual ----------------
__global__ __launch_bounds__(256) void proj_gemm_kernel(
    const short* __restrict__ Wp, const short* __restrict__ aT,
    const float* __restrict__ pbias, const float* __restrict__ x,
    float* __restrict__ out) {
  __shared__ __align__(16) short smem[16384];  // 2 x 128x64 staging (32 KB)
  short* lA = smem;
  short* lB = smem + 8192;
  int bm = blockIdx.x & 3, bn = blockIdx.x >> 2;
  int tid = threadIdx.x, wid = tid >> 6, lane = tid & 63;
  int wr = (wid >> 1) * 64, wc = (wid & 1) * 64;
  int q = lane >> 4, c16 = lane & 15;
  v4f acc[4][4];
#pragma unroll
  for (int i = 0; i < 4; ++i)
#pragma unroll
    for (int j = 0; j < 4; ++j) acc[i][j] = (v4f){0.f, 0.f, 0.f, 0.f};
  gemm_k512_b64(Wp + bm * 128 * 512, aT + bn * 128 * 512, lA, lB, wid, lane, acc);
  int colOff[4];
#pragma unroll
  for (int j = 0; j < 4; ++j) {
    int n = bn * 128 + wc + j * 16 + c16;
    colOff[j] = (n >> 10) * 524288 + (n & 1023);
  }
#pragma unroll
  for (int i = 0; i < 4; ++i)
#pragma unroll
    for (int rr = 0; rr < 4; ++rr) {
      int o = bm * 128 + wr + i * 16 + q * 4 + rr;
      float bs = pbias[o];
      int ro = o * 1024;
#pragma unroll
      for (int j = 0; j < 4; ++j) {
        int a = colOff[j] + ro;
        out[a] = acc[i][j][rr] + bs + x[a];
      }
    }
}

extern "C" void kernel_launch(void* const* d_in, const int* in_sizes, int n_in,
                              void* d_out, int out_size, void* d_ws, size_t ws_size,
                              hipStream_t stream) {
  const float* x = (const float*)d_in[0];
  const float* nw = (const float*)d_in[1];
  const float* nb = (const float*)d_in[2];
  const float* qkvw = (const float*)d_in[3];
  const float* qkvb = (const float*)d_in[4];
  const float* projw = (const float*)d_in[5];
  const float* projb = (const float*)d_in[6];
  float* out = (float*)d_out;
  char* w = (char*)d_ws;
  short* hT = (short*)(w);
  short* aT = (short*)(w + 8388608);
  short* Qb = (short*)(w + 16777216);
  short* Kb = (short*)(w + 25165824);
  short* Vb = (short*)(w + 33554432);
  short* Wq2 = (short*)(w + 41943040);
  short* Wp2 = (short*)(w + 43515904);
  float* b2 = (float*)(w + 44040192);

  hipLaunchKernelGGL(prep_gn_kernel, dim3(4352), dim3(256), 0, stream,
                     qkvw, qkvb, projw, Wq2, Wp2, b2, x, nw, nb, hT);
  hipLaunchKernelGGL(qkv_gemm_kernel, dim3(768), dim3(256), 0, stream,
                     hT, Wq2, b2, Qb, Kb, Vb);
  hipLaunchKernelGGL(attn_kernel, dim3(512), dim3(512), 0, stream, Qb, Kb, Vb, aT);
  hipLaunchKernelGGL(proj_gemm_kernel, dim3(256), dim3(256), 0, stream,
                     Wp2, aT, projb, x, out);
}